// Round 1
// baseline (899.568 us; speedup 1.0000x reference)
//
#include <hip/hip_runtime.h>
#include <math.h>

// Problem constants (B,C,H,W fixed by reference)
constexpr int B = 2, C = 256, H = 512, W = 512, P = 32;
constexpr int NR = H / P;      // 16
constexpr int NC = W / P;      // 16
constexpr int NPOS = NR * NC;  // 256
constexpr float EPS = 1e-5f;

// ---------------------------------------------------------------------------
// K1: 32x32 block-mean pool.  One block per (b, c, br) strip: 32 rows x 512
// cols, coalesced float4 loads; reduces to 16 means (one per bc tile).
// ---------------------------------------------------------------------------
__global__ void pool_kernel(const float* __restrict__ h_past,
                            float* __restrict__ xp) {
    int bid = blockIdx.x;
    int br = bid & 15;
    int c  = (bid >> 4) & 255;
    int b  = bid >> 12;
    const float4* src =
        (const float4*)(h_past + (((size_t)(b * C + c)) * H + (size_t)br * P) * W);
    int t   = threadIdx.x;      // 256 threads
    int f4  = t & 127;          // which float4 within a row (row = 128 float4)
    int row0 = t >> 7;          // 0 or 1
    float s = 0.f;
#pragma unroll
    for (int k = 0; k < 16; ++k) {
        float4 v = src[(row0 + 2 * k) * 128 + f4];
        s += v.x + v.y + v.z + v.w;
    }
    __shared__ float part[256];
    part[t] = s;
    __syncthreads();
    // bc tile = f4/8 ; 16 partials per bc (8 f4 x 2 row-halves)
    if (t < 16) {
        float acc = 0.f;
#pragma unroll
        for (int j = 0; j < 8; ++j)
            acc += part[t * 8 + j] + part[128 + t * 8 + j];
        xp[((b * C + c) * NR + br) * NC + t] = acc * (1.0f / (P * P));
    }
}

// ---------------------------------------------------------------------------
// K2: channel layer-norm per spatial position. One block per (b,p), thread=c.
// Two-pass mean/var (biased), deterministic LDS tree reduction.
// ---------------------------------------------------------------------------
__global__ void norm_kernel(const float* __restrict__ xp,
                            const float* __restrict__ scale,
                            const float* __restrict__ shift,
                            float* __restrict__ xn) {
    int bid = blockIdx.x;       // b*NPOS + p
    int p = bid & 255;
    int b = bid >> 8;
    int c = threadIdx.x;
    float v = xp[(b * C + c) * NPOS + p];
    __shared__ float red[256];
    red[c] = v;
    __syncthreads();
    for (int off = 128; off > 0; off >>= 1) {
        if (c < off) red[c] += red[c + off];
        __syncthreads();
    }
    float mu = red[0] * (1.0f / C);
    __syncthreads();
    float d = v - mu;
    red[c] = d * d;
    __syncthreads();
    for (int off = 128; off > 0; off >>= 1) {
        if (c < off) red[c] += red[c + off];
        __syncthreads();
    }
    float var = red[0] * (1.0f / C);
    float rs = rsqrtf(var + EPS);
    xn[(b * C + c) * NPOS + p] = d * rs * scale[c] + shift[c];
}

// ---------------------------------------------------------------------------
// K3: depthwise 3x3 (pad=1) + bias + exact GELU.  One thread per element.
// ---------------------------------------------------------------------------
__device__ inline float gelu_exact(float x) {
    return 0.5f * x * (1.0f + erff(x * 0.70710678118654752440f));
}

__global__ void dw_kernel(const float* __restrict__ xn,
                          const float* __restrict__ dw_w,
                          const float* __restrict__ dw_b,
                          float* __restrict__ y) {
    int idx = blockIdx.x * 256 + threadIdx.x;
    int w = idx & 15;
    int h = (idx >> 4) & 15;
    int c = (idx >> 8) & 255;
    int b = idx >> 16;
    const float* base = xn + (b * C + c) * NPOS;
    const float* wt = dw_w + c * 9;
    float acc = 0.f;
#pragma unroll
    for (int kh = 0; kh < 3; ++kh) {
        int hh = h + kh - 1;
        if (hh < 0 || hh >= NR) continue;
#pragma unroll
        for (int kw = 0; kw < 3; ++kw) {
            int ww = w + kw - 1;
            if (ww < 0 || ww >= NC) continue;
            acc += base[hh * NC + ww] * wt[kh * 3 + kw];
        }
    }
    y[idx] = gelu_exact(acc + dw_b[c]);
}

// ---------------------------------------------------------------------------
// K4: pointwise 1x1 conv. One block per (b,p); y[b,:,p] staged in LDS; each
// thread computes one output channel (256-length dot, float4).
// ---------------------------------------------------------------------------
__global__ void pw_kernel(const float* __restrict__ y,
                          const float* __restrict__ pw_w,
                          const float* __restrict__ pw_b,
                          float* __restrict__ z) {
    int bid = blockIdx.x;       // b*NPOS + p
    int p = bid & 255;
    int b = bid >> 8;
    int o = threadIdx.x;
    __shared__ float ys[256];
    ys[o] = y[(b * C + o) * NPOS + p];
    __syncthreads();
    const float4* wr = (const float4*)(pw_w + o * C);
    const float4* yv = (const float4*)ys;
    float acc = 0.f;
#pragma unroll 4
    for (int c4 = 0; c4 < 64; ++c4) {
        float4 wv = wr[c4];
        float4 vv = yv[c4];
        acc += wv.x * vv.x + wv.y * vv.y + wv.z * vv.z + wv.w * vv.w;
    }
    z[(b * C + o) * NPOS + p] = acc + pw_b[o];
}

// ---------------------------------------------------------------------------
// K5: broadcast-upsample 16x16 -> 512x512.  float4 splat writes, grid-stride.
// ---------------------------------------------------------------------------
__global__ void up_kernel(const float* __restrict__ z,
                          float4* __restrict__ out) {
    const int total = B * C * H * (W / 4);  // 33,554,432 float4
    for (int idx = blockIdx.x * 256 + threadIdx.x; idx < total;
         idx += gridDim.x * 256) {
        int w4 = idx & 127;          // W/4 = 128
        int h  = (idx >> 7) & 511;
        int bc = idx >> 16;          // b*C + c  (H*W/4 = 65536 per image)
        float v = z[bc * NPOS + (h >> 5) * NC + (w4 >> 3)];
        out[idx] = make_float4(v, v, v, v);
    }
}

extern "C" void kernel_launch(void* const* d_in, const int* in_sizes, int n_in,
                              void* d_out, int out_size, void* d_ws, size_t ws_size,
                              hipStream_t stream) {
    const float* h_past = (const float*)d_in[0];
    const float* scale  = (const float*)d_in[1];
    const float* shift  = (const float*)d_in[2];
    const float* dw_w   = (const float*)d_in[3];
    const float* dw_b   = (const float*)d_in[4];
    const float* pw_w   = (const float*)d_in[5];
    const float* pw_b   = (const float*)d_in[6];
    float* out = (float*)d_out;

    float* ws = (float*)d_ws;
    const int SMALL = B * C * NPOS;  // 131072 elements
    float* xp = ws;
    float* xn = ws + SMALL;
    float* y  = ws + 2 * SMALL;
    float* z  = ws + 3 * SMALL;

    pool_kernel<<<B * C * NR, 256, 0, stream>>>(h_past, xp);
    norm_kernel<<<B * NPOS, 256, 0, stream>>>(xp, scale, shift, xn);
    dw_kernel<<<(B * C * NPOS) / 256, 256, 0, stream>>>(xn, dw_w, dw_b, y);
    pw_kernel<<<B * NPOS, 256, 0, stream>>>(y, pw_w, pw_b, z);
    up_kernel<<<32768, 256, 0, stream>>>(z, (float4*)out);
}